// Round 8
// baseline (809.452 us; speedup 1.0000x reference)
//
#include <hip/hip_runtime.h>
#include <cstdint>
#include <cstddef>

#define M_ROWS 65536
#define N_COLS 1024
#define K_DIM  1024

typedef _Float16 f16x8 __attribute__((ext_vector_type(8)));
typedef float f32x4 __attribute__((ext_vector_type(4)));

// ---------------- prep: scale/bias ----------------
__global__ __launch_bounds__(256) void prep_scale_bias(
    const float* __restrict__ gamma, const float* __restrict__ beta,
    const float* __restrict__ mean, const float* __restrict__ var,
    float* __restrict__ bias, float* __restrict__ scale)
{
  int i = blockIdx.x * 256 + threadIdx.x;
  if (i < N_COLS) {
    float s = gamma[i] * rsqrtf(var[i] + 1e-3f);
    scale[i] = s;
    bias[i] = beta[i] - mean[i] * s;
  }
}

// ---------------- prep: W -> Bp (scaled f16, fragment-permuted for 4-wave fused GEMM) ----
// chunk index = (kt*256 + tid)*32 + kc*16 + fn  (16B chunks), tid = wn*64 + g*16 + li,
// holding Wt[n = wn*256 + fn*16 + li][k = kt*64 + kc*32 + g*8 .. +8].
// => lane's 32 fragments for one kt are contiguous 512B at Bp + tid*512 + kt*131072.
__global__ __launch_bounds__(256) void prep_bp(
    const float* __restrict__ W, const float* __restrict__ scale,
    char* __restrict__ Bp)
{
  __shared__ float tile[64][68];
  int k0 = blockIdx.x * 64, n0 = blockIdx.y * 64;
  int t = threadIdx.x;
  int kr = t >> 2, q = t & 3;
  #pragma unroll
  for (int j = 0; j < 4; ++j) {
    float4 v = *(const float4*)(W + (size_t)(k0 + kr) * N_COLS + n0 + q * 16 + j * 4);
    *(float4*)(&tile[kr][q * 16 + j * 4]) = v;
  }
  __syncthreads();
  int nr = t >> 2;
  int n = n0 + nr;
  float sn = scale[n];
  __align__(16) _Float16 h[16];
  #pragma unroll
  for (int j = 0; j < 16; ++j)
    h[j] = (_Float16)(tile[q * 16 + j][nr] * sn);   // h[j] = Wt[n][k0+q*16+j]
  int wn = n >> 8, fn = (n >> 4) & 15, li = n & 15;
  #pragma unroll
  for (int c = 0; c < 2; ++c) {
    int k = k0 + q * 16 + c * 8;
    int kidx = k >> 3;
    int g = kidx & 3, kc = (kidx >> 2) & 1, kt = kidx >> 3;
    int tg = wn * 64 + g * 16 + li;
    size_t chunk = ((size_t)(kt * 256 + tg)) * 32 + kc * 16 + fn;
    *(uint4*)(Bp + chunk * 16) = *(const uint4*)(&h[c * 8]);
  }
}

// ---------------- prep: A (fp32) -> Af (f16), grid-stride, vectorized ----------------
__global__ __launch_bounds__(256) void conv_a_f16(
    const float* __restrict__ A, _Float16* __restrict__ Af)
{
  const size_t total8 = (size_t)M_ROWS * K_DIM / 8;
  size_t i = (size_t)blockIdx.x * 256 + threadIdx.x;
  const size_t stride = (size_t)gridDim.x * 256;
  for (; i < total8; i += stride) {
    float4 a = *(const float4*)(A + i * 8);
    float4 b = *(const float4*)(A + i * 8 + 4);
    union { _Float16 h[8]; uint4 u; } p;
    p.h[0] = (_Float16)a.x; p.h[1] = (_Float16)a.y;
    p.h[2] = (_Float16)a.z; p.h[3] = (_Float16)a.w;
    p.h[4] = (_Float16)b.x; p.h[5] = (_Float16)b.y;
    p.h[6] = (_Float16)b.z; p.h[7] = (_Float16)b.w;
    *(uint4*)(Af + i * 8) = p.u;
  }
}

// ---------------- fused: z = (Af @ W~ + bias) * priors ; out = sparsemax(z) ----------------
// 256 threads = 4 waves; block = 32 rows x 1024 cols; wave wn owns 256-col band.
// acc[2][16] (128 VGPR). A: gload_lds f16, 3-buffer ring, distance-2 prefetch issued
// AFTER the B loads (vmcnt is in-order: B-waits must not drain the A prefetch).
// Top-of-kt: s_waitcnt vmcnt(1) + raw barrier -> A(kt+1) stays in flight (T4).
// B: L2-resident Bp, one per-lane base, immediate offsets only.
__global__ __launch_bounds__(256, 2) void fused_gemm_sparsemax(
    const _Float16* __restrict__ Af, const char* __restrict__ Bp,
    const float* __restrict__ bias, const float* __restrict__ priors,
    float* __restrict__ out)
{
  __shared__ char asmem[12288];          // 3 x (32 rows x 64 k x f16) = 3 x 4KB
  __shared__ float red[2][32][4];
  __shared__ float redk[2][32][4];

  const int tid = threadIdx.x;
  const int lane = tid & 63, wn = tid >> 6;
  const int li = lane & 15, g = lane >> 4;
  const int m0 = blockIdx.x * 32;

  f32x4 acc[2][16];
  #pragma unroll
  for (int fm = 0; fm < 2; ++fm)
    #pragma unroll
    for (int fn = 0; fn < 16; ++fn) acc[fm][fn] = (f32x4){0.f, 0.f, 0.f, 0.f};

  // ---- A staging: 256 threads cover 32x64 f16 tile (256 x 16B chunks) ----
  const int rl = tid >> 3, c8 = tid & 7;
  const char* asrc = (const char*)(Af + (size_t)(m0 + rl) * K_DIM)
                     + ((c8 * 16) ^ ((rl & 7) << 4));   // inverse-swizzled source (rule 21)
  auto stageA = [&](int kt, int buf) {
    __builtin_amdgcn_global_load_lds(
        (const __attribute__((address_space(1))) unsigned int*)(asrc + kt * 128),
        (__attribute__((address_space(3))) unsigned int*)(&asmem[buf * 4096 + tid * 16]),
        16, 0, 0);
  };

  const char* bkt = Bp + (size_t)tid * 512;
  const int aswz = (li & 7) << 4;

  stageA(0, 0);
  stageA(1, 1);

  int cur = 0;
  for (int kt = 0; kt < 16; ++kt) {
    if (kt < 15) asm volatile("s_waitcnt vmcnt(1)" ::: "memory");  // A(kt) done, A(kt+1) in flight
    else         asm volatile("s_waitcnt vmcnt(0)" ::: "memory");
    __builtin_amdgcn_s_barrier();

    const int abase = cur * 4096;
    #pragma unroll
    for (int kc = 0; kc < 2; ++kc) {
      f16x8 bf[16];
      #pragma unroll
      for (int fn = 0; fn < 16; ++fn)
        bf[fn] = *(const f16x8*)(bkt + kc * 256 + fn * 16);
      const int koff = kc * 64 + g * 16;
      f16x8 af0 = *(const f16x8*)(&asmem[abase + li * 128 + (koff ^ aswz)]);
      f16x8 af1 = *(const f16x8*)(&asmem[abase + (16 + li) * 128 + (koff ^ aswz)]);
      #pragma unroll
      for (int fn = 0; fn < 16; ++fn) {
        acc[0][fn] = __builtin_amdgcn_mfma_f32_16x16x32_f16(af0, bf[fn], acc[0][fn], 0, 0, 0);
        acc[1][fn] = __builtin_amdgcn_mfma_f32_16x16x32_f16(af1, bf[fn], acc[1][fn], 0, 0, 0);
      }
    }
    bkt += 131072;
    // distance-2 A prefetch, issued AFTER this kt's B loads (keeps it newest in vmcnt queue)
    if (kt < 14) stageA(kt + 2, (kt + 2) % 3);
    asm volatile("s_waitcnt lgkmcnt(0)" ::: "memory");   // af reads retired before buffer reuse
    __builtin_amdgcn_s_barrier();
    cur = (cur == 2) ? 0 : cur + 1;
  }

  // ---- epilogue: z = (acc + bias) * priors, in registers ----
  float bv[16];
  #pragma unroll
  for (int fn = 0; fn < 16; ++fn) bv[fn] = bias[wn * 256 + fn * 16 + li];

  #pragma unroll
  for (int fm = 0; fm < 2; ++fm)
    #pragma unroll
    for (int r = 0; r < 4; ++r) {
      const float* pp = priors + (size_t)(m0 + fm * 16 + g * 4 + r) * N_COLS + wn * 256 + li;
      #pragma unroll
      for (int fn = 0; fn < 16; ++fn)
        acc[fm][fn][r] = (acc[fm][fn][r] + bv[fn]) * pp[fn * 16];
    }

  // ---- sparsemax on register-resident z (proven R3 numerics) ----
  float mx[2][4];
  #pragma unroll
  for (int fm = 0; fm < 2; ++fm)
    #pragma unroll
    for (int r = 0; r < 4; ++r) {
      float m = acc[fm][0][r];
      #pragma unroll
      for (int fn = 1; fn < 16; ++fn) m = fmaxf(m, acc[fm][fn][r]);
      m = fmaxf(m, __shfl_xor(m, 1, 64));
      m = fmaxf(m, __shfl_xor(m, 2, 64));
      m = fmaxf(m, __shfl_xor(m, 4, 64));
      m = fmaxf(m, __shfl_xor(m, 8, 64));
      mx[fm][r] = m;
    }
  if (li == 0) {
    #pragma unroll
    for (int fm = 0; fm < 2; ++fm)
      #pragma unroll
      for (int r = 0; r < 4; ++r)
        red[0][fm * 16 + g * 4 + r][wn] = mx[fm][r];
  }
  __syncthreads();

  float lo[2][4], hi[2][4];
  #pragma unroll
  for (int fm = 0; fm < 2; ++fm)
    #pragma unroll
    for (int r = 0; r < 4; ++r) {
      float4 q = *(const float4*)(&red[0][fm * 16 + g * 4 + r][0]);
      float M = fmaxf(fmaxf(q.x, q.y), fmaxf(q.z, q.w));
      lo[fm][r] = M - 1.0f;
      hi[fm][r] = M;
    }

  float tt[2][4];
  for (int it = 0; it < 12; ++it) {
    const int b = (it + 1) & 1;
    float sv[2][4];
    #pragma unroll
    for (int fm = 0; fm < 2; ++fm)
      #pragma unroll
      for (int r = 0; r < 4; ++r) {
        float t = 0.5f * (lo[fm][r] + hi[fm][r]);
        tt[fm][r] = t;
        float s = 0.f;
        #pragma unroll
        for (int fn = 0; fn < 16; ++fn) s += fmaxf(acc[fm][fn][r] - t, 0.f);
        s += __shfl_xor(s, 1, 64);
        s += __shfl_xor(s, 2, 64);
        s += __shfl_xor(s, 4, 64);
        s += __shfl_xor(s, 8, 64);
        sv[fm][r] = s;
      }
    if (li == 0) {
      #pragma unroll
      for (int fm = 0; fm < 2; ++fm)
        #pragma unroll
        for (int r = 0; r < 4; ++r)
          red[b][fm * 16 + g * 4 + r][wn] = sv[fm][r];
    }
    __syncthreads();
    #pragma unroll
    for (int fm = 0; fm < 2; ++fm)
      #pragma unroll
      for (int r = 0; r < 4; ++r) {
        float4 q = *(const float4*)(&red[b][fm * 16 + g * 4 + r][0]);
        float S = (q.x + q.y) + (q.z + q.w);
        if (S >= 1.f) lo[fm][r] = tt[fm][r]; else hi[fm][r] = tt[fm][r];
      }
  }

  float tv[2][4];
  #pragma unroll
  for (int fm = 0; fm < 2; ++fm)
    #pragma unroll
    for (int r = 0; r < 4; ++r) tv[fm][r] = lo[fm][r];

  for (int nit = 0; nit < 2; ++nit) {
    const int b = (nit + 1) & 1;
    float sv[2][4], kv[2][4];
    #pragma unroll
    for (int fm = 0; fm < 2; ++fm)
      #pragma unroll
      for (int r = 0; r < 4; ++r) {
        float s = 0.f, k = 0.f;
        float t = tv[fm][r];
        #pragma unroll
        for (int fn = 0; fn < 16; ++fn) {
          float d = acc[fm][fn][r];
          bool gt = d > t;
          s += gt ? d : 0.f;
          k += gt ? 1.f : 0.f;
        }
        s += __shfl_xor(s, 1, 64); k += __shfl_xor(k, 1, 64);
        s += __shfl_xor(s, 2, 64); k += __shfl_xor(k, 2, 64);
        s += __shfl_xor(s, 4, 64); k += __shfl_xor(k, 4, 64);
        s += __shfl_xor(s, 8, 64); k += __shfl_xor(k, 8, 64);
        sv[fm][r] = s; kv[fm][r] = k;
      }
    if (li == 0) {
      #pragma unroll
      for (int fm = 0; fm < 2; ++fm)
        #pragma unroll
        for (int r = 0; r < 4; ++r) {
          red[b][fm * 16 + g * 4 + r][wn] = sv[fm][r];
          redk[b][fm * 16 + g * 4 + r][wn] = kv[fm][r];
        }
    }
    __syncthreads();
    #pragma unroll
    for (int fm = 0; fm < 2; ++fm)
      #pragma unroll
      for (int r = 0; r < 4; ++r) {
        float4 q = *(const float4*)(&red[b][fm * 16 + g * 4 + r][0]);
        float4 qk = *(const float4*)(&redk[b][fm * 16 + g * 4 + r][0]);
        float S = (q.x + q.y) + (q.z + q.w);
        float K = (qk.x + qk.y) + (qk.z + qk.w);
        tv[fm][r] = (S - 1.f) / K;   // K >= 1 (row max stays in support)
      }
  }

  #pragma unroll
  for (int fm = 0; fm < 2; ++fm)
    #pragma unroll
    for (int r = 0; r < 4; ++r) {
      float* op = out + (size_t)(m0 + fm * 16 + g * 4 + r) * N_COLS + wn * 256 + li;
      float t = tv[fm][r];
      #pragma unroll
      for (int fn = 0; fn < 16; ++fn)
        op[fn * 16] = fmaxf(acc[fm][fn][r] - t, 0.f);
    }
}

// ---------------- FALLBACK path (ws too small): R2 split kernels ----------------
__global__ __launch_bounds__(256) void prep_wt(
    const float* __restrict__ W, const float* __restrict__ scale,
    _Float16* __restrict__ Wt)
{
  __shared__ float tile[64][68];
  int k0 = blockIdx.x * 64, n0 = blockIdx.y * 64;
  int t = threadIdx.x;
  int kr = t >> 2, q = t & 3;
  #pragma unroll
  for (int j = 0; j < 4; ++j) {
    float4 v = *(const float4*)(W + (size_t)(k0 + kr) * N_COLS + n0 + q * 16 + j * 4);
    *(float4*)(&tile[kr][q * 16 + j * 4]) = v;
  }
  __syncthreads();
  int nr = t >> 2;
  float sn = scale[n0 + nr];
  __align__(16) _Float16 h[16];
  #pragma unroll
  for (int j = 0; j < 16; ++j)
    h[j] = (_Float16)(tile[q * 16 + j][nr] * sn);
  uint4* dst = (uint4*)(Wt + (size_t)(n0 + nr) * K_DIM + k0 + q * 16);
  dst[0] = *(uint4*)(&h[0]);
  dst[1] = *(uint4*)(&h[8]);
}

__global__ __launch_bounds__(256, 2) void gemm_f16(
    const float* __restrict__ A, const _Float16* __restrict__ Wt,
    const float* __restrict__ bias, const float* __restrict__ priors,
    float* __restrict__ out)
{
  __shared__ char smem[65536];
  const int tid = threadIdx.x;
  const int lane = tid & 63, wid = tid >> 6;
  const int wm = wid >> 1, wnn = wid & 1;
  int orig = blockIdx.x;
  int wgid = (orig & 7) * 512 + (orig >> 3);
  int mb = wgid >> 3, nb = wgid & 7;
  const int m0 = mb * 128, n0 = nb * 128;
  f32x4 acc[4][4];
  #pragma unroll
  for (int i = 0; i < 4; ++i)
    #pragma unroll
    for (int j = 0; j < 4; ++j) acc[i][j] = (f32x4){0.f, 0.f, 0.f, 0.f};
  float4 areg[8];
  auto loadA = [&](int kt) {
    #pragma unroll
    for (int j = 0; j < 8; ++j) {
      int f = j * 256 + tid;
      int ml = f >> 4, k4 = (f & 15) << 2;
      areg[j] = *(const float4*)(A + (size_t)(m0 + ml) * K_DIM + kt * 64 + k4);
    }
  };
  auto storeA = [&](int buf) {
    int base = buf * 16384;
    #pragma unroll
    for (int j = 0; j < 8; ++j) {
      int f = j * 256 + tid;
      int ml = f >> 4, k4 = (f & 15) << 2;
      int off = ml * 128 + ((k4 * 2) ^ ((ml & 7) << 4));
      union { _Float16 h[4]; uint2 u; } p;
      p.h[0] = (_Float16)areg[j].x; p.h[1] = (_Float16)areg[j].y;
      p.h[2] = (_Float16)areg[j].z; p.h[3] = (_Float16)areg[j].w;
      *(uint2*)(&smem[base + off]) = p.u;
    }
  };
  auto issueB = [&](int kt, int buf) {
    int base = 32768 + buf * 16384;
    #pragma unroll
    for (int t4 = 0; t4 < 4; ++t4) {
      int ch = t4 * 256 + tid;
      int nl = ch >> 3, c = ch & 7;
      const char* src = (const char*)Wt + ((size_t)(n0 + nl) * K_DIM + kt * 64) * 2
          + ((c * 16) ^ ((nl & 7) << 4));
      __builtin_amdgcn_global_load_lds(
          (const __attribute__((address_space(1))) unsigned int*)src,
          (__attribute__((address_space(3))) unsigned int*)(&smem[base + ch * 16]),
          16, 0, 0);
    }
  };
  loadA(0); issueB(0, 0); storeA(0);
  __syncthreads();
  for (int kt = 0; kt < 16; ++kt) {
    int curb = kt & 1, nxt = curb ^ 1;
    if (kt < 15) { loadA(kt + 1); issueB(kt + 1, nxt); }
    int ab = curb * 16384, bb = 32768 + curb * 16384;
    #pragma unroll
    for (int kc = 0; kc < 2; ++kc) {
      int k2 = (kc * 32 + ((lane >> 4) * 8)) * 2;
      f16x8 af[4], bfr[4];
      #pragma unroll
      for (int fm = 0; fm < 4; ++fm) {
        int rl2 = wm * 64 + fm * 16 + (lane & 15);
        af[fm] = *(const f16x8*)(&smem[ab + rl2 * 128 + (k2 ^ ((rl2 & 7) << 4))]);
      }
      #pragma unroll
      for (int fn = 0; fn < 4; ++fn) {
        int nl = wnn * 64 + fn * 16 + (lane & 15);
        bfr[fn] = *(const f16x8*)(&smem[bb + nl * 128 + (k2 ^ ((nl & 7) << 4))]);
      }
      #pragma unroll
      for (int fm = 0; fm < 4; ++fm)
        #pragma unroll
        for (int fn = 0; fn < 4; ++fn)
          acc[fm][fn] = __builtin_amdgcn_mfma_f32_16x16x32_f16(af[fm], bfr[fn], acc[fm][fn], 0, 0, 0);
    }
    if (kt < 15) storeA(nxt);
    __syncthreads();
  }
  #pragma unroll
  for (int fn = 0; fn < 4; ++fn) {
    int col = n0 + wnn * 64 + fn * 16 + (lane & 15);
    float bvv = bias[col];
    #pragma unroll
    for (int fm = 0; fm < 4; ++fm) {
      int row0 = m0 + wm * 64 + fm * 16 + ((lane >> 4) << 2);
      #pragma unroll
      for (int r = 0; r < 4; ++r) {
        size_t idx = (size_t)(row0 + r) * N_COLS + col;
        out[idx] = (acc[fm][fn][r] + bvv) * priors[idx];
      }
    }
  }
}

__global__ __launch_bounds__(256) void sparsemax_rows(float* __restrict__ z)
{
  const int lane = threadIdx.x & 63, wid = threadIdx.x >> 6;
  const size_t row = (size_t)blockIdx.x * 4 + wid;
  float* p = z + row * N_COLS;
  float v[16];
  #pragma unroll
  for (int j = 0; j < 4; ++j) {
    float4 t = *(const float4*)(p + j * 256 + lane * 4);
    v[j * 4 + 0] = t.x; v[j * 4 + 1] = t.y; v[j * 4 + 2] = t.z; v[j * 4 + 3] = t.w;
  }
  float mx = v[0];
  #pragma unroll
  for (int j = 1; j < 16; ++j) mx = fmaxf(mx, v[j]);
  #pragma unroll
  for (int m = 1; m <= 32; m <<= 1) mx = fmaxf(mx, __shfl_xor(mx, m, 64));
  float lo = mx - 1.0f, hi = mx;
  for (int it = 0; it < 12; ++it) {
    float tau = 0.5f * (lo + hi);
    float s = 0.f;
    #pragma unroll
    for (int j = 0; j < 16; ++j) s += fmaxf(v[j] - tau, 0.f);
    #pragma unroll
    for (int m = 1; m <= 32; m <<= 1) s += __shfl_xor(s, m, 64);
    if (s >= 1.f) lo = tau; else hi = tau;
  }
  float tau = lo;
  #pragma unroll
  for (int it = 0; it < 2; ++it) {
    float s = 0.f, k = 0.f;
    #pragma unroll
    for (int j = 0; j < 16; ++j) {
      bool gg = v[j] > tau;
      s += gg ? v[j] : 0.f;
      k += gg ? 1.f : 0.f;
    }
    #pragma unroll
    for (int m = 1; m <= 32; m <<= 1) { s += __shfl_xor(s, m, 64); k += __shfl_xor(k, m, 64); }
    tau = (s - 1.f) / k;
  }
  #pragma unroll
  for (int j = 0; j < 4; ++j) {
    float4 t;
    t.x = fmaxf(v[j * 4 + 0] - tau, 0.f);
    t.y = fmaxf(v[j * 4 + 1] - tau, 0.f);
    t.z = fmaxf(v[j * 4 + 2] - tau, 0.f);
    t.w = fmaxf(v[j * 4 + 3] - tau, 0.f);
    *(float4*)(p + j * 256 + lane * 4) = t;
  }
}

// ---------------- launch ----------------
extern "C" void kernel_launch(void* const* d_in, const int* in_sizes, int n_in,
                              void* d_out, int out_size, void* d_ws, size_t ws_size,
                              hipStream_t stream) {
  const float* inputs = (const float*)d_in[0];
  const float* priors = (const float*)d_in[1];
  const float* W      = (const float*)d_in[2];
  const float* gamma  = (const float*)d_in[3];
  const float* beta   = (const float*)d_in[4];
  const float* mean   = (const float*)d_in[5];
  const float* var    = (const float*)d_in[6];
  float* out = (float*)d_out;

  char* ws = (char*)d_ws;
  float* bias  = (float*)ws;                 // 4 KB
  float* scale = (float*)(ws + 4096);        // 4 KB
  char*  Bp    = ws + 8192;                  // 2 MB (fragment-permuted) or Wt (fallback)
  const size_t AF_OFF = 8192 + (size_t)N_COLS * K_DIM * 2;
  _Float16* Af = (_Float16*)(ws + AF_OFF);   // 134 MB, [M][K] f16
  const size_t need = AF_OFF + (size_t)M_ROWS * K_DIM * 2;

  prep_scale_bias<<<4, 256, 0, stream>>>(gamma, beta, mean, var, bias, scale);

  if (ws_size >= need) {
    prep_bp<<<dim3(16, 16), 256, 0, stream>>>(W, scale, Bp);
    conv_a_f16<<<2048, 256, 0, stream>>>(inputs, Af);
    fused_gemm_sparsemax<<<M_ROWS / 32, 256, 0, stream>>>(Af, Bp, bias, priors, out);
  } else {
    prep_wt<<<dim3(16, 16), 256, 0, stream>>>(W, scale, (_Float16*)Bp);
    gemm_f16<<<4096, 256, 0, stream>>>(inputs, (_Float16*)Bp, bias, priors, out);
    sparsemax_rows<<<16384, 256, 0, stream>>>(out);
  }
}